// Round 11
// baseline (470.444 us; speedup 1.0000x reference)
//
#include <hip/hip_runtime.h>

#define FFT_N   4096
#define THREADS 256

// Complex as clang ext-vector -> CDNA packed FP32 (v_pk_add/mul/fma with
// op_sel/neg modifiers). cmul = 2 packed ops.
typedef float cf2 __attribute__((ext_vector_type(2)));

__device__ __forceinline__ cf2 mkc(float x, float y) { cf2 r; r.x = x; r.y = y; return r; }

__device__ __forceinline__ cf2 cmul(cf2 a, cf2 b) {
    return a.x * b + mkc(-a.y, a.y) * b.yx;
}

template<int S>
__device__ __forceinline__ cf2 muli(cf2 z) {
    return (S < 0) ? mkc(z.y, -z.x) : mkc(-z.y, z.x);
}

template<int S>
__device__ __forceinline__ void dft4(cf2 a0, cf2 a1, cf2 a2, cf2 a3,
                                     cf2& y0, cf2& y1, cf2& y2, cf2& y3) {
    cf2 e0 = a0 + a2, e1 = a1 + a3;
    cf2 o0 = a0 - a2, o1 = muli<S>(a1 - a3);
    y0 = e0 + e1; y2 = e0 - e1;
    y1 = o0 + o1; y3 = o0 - o1;
}

// 16-point DFT in registers: a[k] <- sum_n a[n] exp(S*2pi*i*n*k/16)
template<int S>
__device__ __forceinline__ void dft16(cf2* a) {
    const float C1 = 0.92387953251128674f;   // cos(pi/8)
    const float S1 = 0.38268343236508978f;   // sin(pi/8)
    const float R2 = 0.70710678118654752f;
    const float sg = (S < 0) ? -1.0f : 1.0f;
    const cf2 w1 = mkc( C1,  sg*S1);
    const cf2 w2 = mkc( R2,  sg*R2);
    const cf2 w3 = mkc( S1,  sg*C1);
    const cf2 w6 = mkc(-R2,  sg*R2);
    const cf2 w9 = mkc(-C1, -sg*S1);
    cf2 t[16];
    dft4<S>(a[0], a[4], a[8],  a[12], t[0],  t[1],  t[2],  t[3]);
    dft4<S>(a[1], a[5], a[9],  a[13], t[4],  t[5],  t[6],  t[7]);
    dft4<S>(a[2], a[6], a[10], a[14], t[8],  t[9],  t[10], t[11]);
    dft4<S>(a[3], a[7], a[11], a[15], t[12], t[13], t[14], t[15]);
    t[5]  = cmul(t[5],  w1);  t[6]  = cmul(t[6],  w2);  t[7]  = cmul(t[7],  w3);
    t[9]  = cmul(t[9],  w2);  t[10] = muli<S>(t[10]);   t[11] = cmul(t[11], w6);
    t[13] = cmul(t[13], w3);  t[14] = cmul(t[14], w6);  t[15] = cmul(t[15], w9);
    dft4<S>(t[0], t[4], t[8],  t[12], a[0], a[4], a[8],  a[12]);
    dft4<S>(t[1], t[5], t[9],  t[13], a[1], a[5], a[9],  a[13]);
    dft4<S>(t[2], t[6], t[10], t[14], a[2], a[6], a[10], a[14]);
    dft4<S>(t[3], t[7], t[11], t[15], a[3], a[7], a[11], a[15]);
}

// Build w[k] = exp(S*2pi*i*p*k/M), k=1..15 (tree powering, shared per phase).
template<int S>
__device__ __forceinline__ void build_tw(cf2* w, int p, float invM) {
    float ang = 6.283185307179586f * (float)p * invM;
    if (S < 0) ang = -ang;
    float s, c;
    __sincosf(ang, &s, &c);
    w[1] = mkc(c, s);
    w[2] = cmul(w[1], w[1]);
    w[3] = cmul(w[2], w[1]);
    w[4] = cmul(w[2], w[2]);
    #pragma unroll
    for (int k = 5; k < 16; ++k) w[k] = cmul(w[k-4], w[4]);
}
__device__ __forceinline__ void apply_tw(cf2* R, const cf2* w) {
    #pragma unroll
    for (int k = 1; k < 16; ++k) R[k] = cmul(R[k], w[k]);
}

// float2-slot swizzle (r2-verified): bits 1..3 ^= bits 4..6. Patterns
// stride-256 and stride-16-in-256 land exactly 4 lanes/bank-pair (b64
// conflict-free floor); contiguous-16 lands 8/pair = free 2-way (m136).
// Preserves 16-slot-group membership -> group-local exchanges stay wave-local.
__device__ __forceinline__ int swz(int i) { return i ^ (((i >> 4) & 7) << 1); }

// Wave-local LDS fence (B->C / C->D exchanges live inside one 16-thread group).
__device__ __forceinline__ void wave_lds_fence() {
    asm volatile("s_waitcnt lgkmcnt(0)" ::: "memory");
}

__global__ __launch_bounds__(THREADS, 3) void afdf_fft_kernel(
    const float* __restrict__ x,   // (B, 4096, 2)
    const float* __restrict__ A,   // (1, 4096, 2)
    const float* __restrict__ D,   // (1, 4096, 2)
    float* __restrict__ out)       // (B, 4096, 2)
{
    // ONE row transits LDS at a time: 4096 float2 = 32 KiB -> 3+ blocks/CU.
    // Staggered schedule: while row1's writes drain, row0's compute runs.
    __shared__ __align__(16) cf2 sh[FFT_N];

    const int t = threadIdx.x;
    const size_t rb = (size_t)blockIdx.x * 2 * FFT_N;
    const cf2* __restrict__ xr0 = (const cf2*)x + rb;
    const cf2* __restrict__ xr1 = xr0 + FFT_N;
    const cf2* __restrict__ Ac  = (const cf2*)A;
    const cf2* __restrict__ Dc  = (const cf2*)D;
    cf2* __restrict__ o0        = (cf2*)out + rb;
    cf2* __restrict__ o1        = o0 + FFT_N;

    const int gb = (t >> 4) * 256, p2 = t & 15;
    cf2 w[16];

    // ---- Phase A: load + A-scale + S1 (stride-256), both rows ----
    cf2 r0[16], r1[16];
    #pragma unroll
    for (int n = 0; n < 16; ++n) {
        cf2 a = Ac[t + 256*n];
        r0[n] = a * xr0[t + 256*n];
        r1[n] = a * xr1[t + 256*n];
    }
    dft16<-1>(r0); dft16<-1>(r1);
    build_tw<-1>(w, t, 1.0f/4096.0f);
    apply_tw(r0, w); apply_tw(r1, w);

    // ---- A->B exchange (full transpose), staggered ----
    #pragma unroll
    for (int k = 0; k < 16; ++k) sh[swz(t + 256*k)] = r0[k];
    __syncthreads();
    cf2 b0[16];
    #pragma unroll
    for (int n = 0; n < 16; ++n) b0[n] = sh[swz(gb + p2 + 16*n)];
    __syncthreads();                       // WAR before overwrite
    #pragma unroll
    for (int k = 0; k < 16; ++k) sh[swz(t + 256*k)] = r1[k];
    // compute B on row0 while row1's writes drain
    dft16<-1>(b0);
    build_tw<-1>(w, p2, 1.0f/256.0f);
    apply_tw(b0, w);
    __syncthreads();
    cf2 b1[16];
    #pragma unroll
    for (int n = 0; n < 16; ++n) b1[n] = sh[swz(gb + p2 + 16*n)];
    dft16<-1>(b1);
    apply_tw(b1, w);

    // ---- B->C exchange (group-local), staggered ----
    #pragma unroll
    for (int k = 0; k < 16; ++k) sh[swz(gb + p2 + 16*k)] = b0[k];
    wave_lds_fence();
    cf2 c0[16];
    #pragma unroll
    for (int n = 0; n < 16; ++n) c0[n] = sh[swz(16*t + n)];
    wave_lds_fence();                      // WAR
    #pragma unroll
    for (int k = 0; k < 16; ++k) sh[swz(gb + p2 + 16*k)] = b1[k];
    // D-scale constants (shared by both rows; 1/N folded)
    cf2 dreg[16];
    {
        const int k1 = t >> 4, k2 = t & 15;
        const float inv = 1.0f / 4096.0f;
        #pragma unroll
        for (int k3 = 0; k3 < 16; ++k3) dreg[k3] = Dc[256*k3 + 16*k2 + k1] * inv;
    }
    // compute C on row0 while row1's writes drain
    dft16<-1>(c0);
    #pragma unroll
    for (int k3 = 0; k3 < 16; ++k3) c0[k3] = dreg[k3] * c0[k3];
    dft16<+1>(c0);
    wave_lds_fence();
    cf2 c1[16];
    #pragma unroll
    for (int n = 0; n < 16; ++n) c1[n] = sh[swz(16*t + n)];
    dft16<-1>(c1);
    #pragma unroll
    for (int k3 = 0; k3 < 16; ++k3) c1[k3] = dreg[k3] * c1[k3];
    dft16<+1>(c1);

    // ---- C->D exchange (group-local), staggered ----
    #pragma unroll
    for (int k = 0; k < 16; ++k) sh[swz(16*t + k)] = c0[k];
    wave_lds_fence();
    cf2 d0[16];
    #pragma unroll
    for (int n = 0; n < 16; ++n) d0[n] = sh[swz(gb + p2 + 16*n)];
    wave_lds_fence();                      // WAR
    #pragma unroll
    for (int k = 0; k < 16; ++k) sh[swz(16*t + k)] = c1[k];
    // compute D on row0 while row1's writes drain
    build_tw<+1>(w, p2, 1.0f/256.0f);
    apply_tw(d0, w);
    dft16<+1>(d0);
    wave_lds_fence();
    cf2 d1[16];
    #pragma unroll
    for (int n = 0; n < 16; ++n) d1[n] = sh[swz(gb + p2 + 16*n)];
    apply_tw(d1, w);
    dft16<+1>(d1);

    // ---- D->E exchange (full transpose), staggered ----
    #pragma unroll
    for (int k = 0; k < 16; ++k) sh[swz(gb + p2 + 16*k)] = d0[k];
    __syncthreads();
    cf2 e0[16];
    #pragma unroll
    for (int k = 0; k < 16; ++k) e0[k] = sh[swz(t + 256*k)];
    __syncthreads();                       // WAR
    #pragma unroll
    for (int k = 0; k < 16; ++k) sh[swz(gb + p2 + 16*k)] = d1[k];
    // compute E + store row0 while row1's writes drain
    build_tw<+1>(w, t, 1.0f/4096.0f);
    apply_tw(e0, w);
    dft16<+1>(e0);
    #pragma unroll
    for (int n = 0; n < 16; ++n) o0[t + 256*n] = e0[n];
    __syncthreads();
    cf2 e1[16];
    #pragma unroll
    for (int k = 0; k < 16; ++k) e1[k] = sh[swz(t + 256*k)];
    apply_tw(e1, w);
    dft16<+1>(e1);
    #pragma unroll
    for (int n = 0; n < 16; ++n) o1[t + 256*n] = e1[n];
}

extern "C" void kernel_launch(void* const* d_in, const int* in_sizes, int n_in,
                              void* d_out, int out_size, void* d_ws, size_t ws_size,
                              hipStream_t stream) {
    (void)in_sizes; (void)n_in; (void)out_size; (void)d_ws; (void)ws_size;
    const float* x = (const float*)d_in[0];
    const float* A = (const float*)d_in[1];
    const float* D = (const float*)d_in[2];
    float* out = (float*)d_out;

    // 8192 rows, 2 rows per block
    afdf_fft_kernel<<<dim3(4096), dim3(THREADS), 0, stream>>>(x, A, D, out);
}